// Round 1
// baseline (56.156 us; speedup 1.0000x reference)
//
#include <hip/hip_runtime.h>
#include <math.h>

#define SEQ 8192
#define DIM 512  // 2*HIDDEN

// Kernel A: a[i] = sum_d tanhf(e[i][d]) * w[d]
// One wave (64 lanes) per row; each lane reads 8 contiguous floats (2x float4).
__global__ __launch_bounds__(256) void ca_compute_a(
    const float* __restrict__ e, const float* __restrict__ w,
    float* __restrict__ a) {
    const int wave = threadIdx.x >> 6;   // 0..3
    const int lane = threadIdx.x & 63;
    const int row  = blockIdx.x * 4 + wave;
    const float* er = e + (size_t)row * DIM + lane * 8;
    const float* wr = w + lane * 8;

    float4 e0 = *reinterpret_cast<const float4*>(er);
    float4 e1 = *reinterpret_cast<const float4*>(er + 4);
    float4 w0 = *reinterpret_cast<const float4*>(wr);
    float4 w1 = *reinterpret_cast<const float4*>(wr + 4);

    float sum = tanhf(e0.x) * w0.x + tanhf(e0.y) * w0.y +
                tanhf(e0.z) * w0.z + tanhf(e0.w) * w0.w +
                tanhf(e1.x) * w1.x + tanhf(e1.y) * w1.y +
                tanhf(e1.z) * w1.z + tanhf(e1.w) * w1.w;

    #pragma unroll
    for (int off = 32; off; off >>= 1) sum += __shfl_down(sum, off, 64);
    if (lane == 0) a[row] = sum;
}

// Kernel B: p = softmax(a) over all SEQ elements. Single block of 1024 threads.
__global__ __launch_bounds__(1024) void ca_softmax(
    const float* __restrict__ a, float* __restrict__ p) {
    __shared__ float red[16];
    __shared__ float bcast;
    const int tid = threadIdx.x;

    float vals[8];
    float m = -INFINITY;
    #pragma unroll
    for (int k = 0; k < 8; ++k) {
        vals[k] = a[tid + k * 1024];
        m = fmaxf(m, vals[k]);
    }
    #pragma unroll
    for (int off = 32; off; off >>= 1) m = fmaxf(m, __shfl_down(m, off, 64));
    if ((tid & 63) == 0) red[tid >> 6] = m;
    __syncthreads();
    if (tid == 0) {
        float v = red[0];
        #pragma unroll
        for (int i = 1; i < 16; ++i) v = fmaxf(v, red[i]);
        bcast = v;
    }
    __syncthreads();
    m = bcast;

    float s = 0.f;
    #pragma unroll
    for (int k = 0; k < 8; ++k) {
        vals[k] = expf(vals[k] - m);
        s += vals[k];
    }
    __syncthreads();  // red[] reuse
    #pragma unroll
    for (int off = 32; off; off >>= 1) s += __shfl_down(s, off, 64);
    if ((tid & 63) == 0) red[tid >> 6] = s;
    __syncthreads();
    if (tid == 0) {
        float v = 0.f;
        #pragma unroll
        for (int i = 0; i < 16; ++i) v += red[i];
        bcast = v;
    }
    __syncthreads();
    const float inv = 1.0f / bcast;
    #pragma unroll
    for (int k = 0; k < 8; ++k) p[tid + k * 1024] = vals[k] * inv;
}

// Kernel C: out[i][j] = p[i] for all j. Pure write-bandwidth fill.
// One block per row; float4 stores, coalesced across the row.
__global__ __launch_bounds__(256) void ca_broadcast(
    const float* __restrict__ p, float4* __restrict__ out) {
    const int row = blockIdx.x;
    const float v = p[row];
    const float4 f = make_float4(v, v, v, v);
    float4* o = out + (size_t)row * (SEQ / 4);
    #pragma unroll
    for (int k = 0; k < (SEQ / 4) / 256; ++k)
        o[threadIdx.x + k * 256] = f;
}

extern "C" void kernel_launch(void* const* d_in, const int* in_sizes, int n_in,
                              void* d_out, int out_size, void* d_ws, size_t ws_size,
                              hipStream_t stream) {
    const float* enc = (const float*)d_in[0];   // [SEQ, DIM] fp32
    const float* w   = (const float*)d_in[1];   // [2*DIM] fp32 (only first DIM used)
    // d_in[2] = bias: cancels in softmax over axis 0.
    float* out = (float*)d_out;                 // [SEQ, SEQ] fp32

    float* a = (float*)d_ws;                    // SEQ floats
    float* p = a + SEQ;                         // SEQ floats

    ca_compute_a<<<SEQ / 4, 256, 0, stream>>>(enc, w, a);
    ca_softmax<<<1, 1024, 0, stream>>>(a, p);
    ca_broadcast<<<SEQ, 256, 0, stream>>>(p, (float4*)out);
}